// Round 5
// baseline (667.659 us; speedup 1.0000x reference)
//
#include <hip/hip_runtime.h>
#include <hip/hip_bf16.h>

#define NBR   8
#define DV    256    // VOCAB
#define FF    1024   // FFN
#define ROWS  128    // rows per block
#define NCHUNK 16    // FFN chunks of 64

// LDS (bytes): B1 dbuf 2x32K @0 | B2 dbuf 2x32K @64K | Hs dbuf 2x16K @128K = 160 KiB
#define L_B1 0
#define L_B2 65536
#define L_HS 131072
#define LDS_BYTES 163840

using bf16x8 = __attribute__((ext_vector_type(8))) short;
using f32x4  = __attribute__((ext_vector_type(4))) float;

__device__ __forceinline__ unsigned short f2bf(float f) {
    unsigned int u = __builtin_bit_cast(unsigned int, f);
    unsigned int r = (u + 0x7fffu + ((u >> 16) & 1u)) >> 16;
    return (unsigned short)r;
}
// gelu(x) ~= x * sigmoid(1.595769122x + 0.0713548163x^3), exp2 domain
__device__ __forceinline__ float gelu_fast(float x) {
    float x2 = x * x;
    float z  = x * fmaf(x2, -0.1029434959f, -2.3022078770f);
    float e  = __builtin_amdgcn_exp2f(z);
    return x * __builtin_amdgcn_rcpf(1.0f + e);
}

#define GLL(gsrc, ldst) __builtin_amdgcn_global_load_lds((const unsigned int*)(gsrc), (unsigned int*)(ldst), 16, 0, 0)
#define MFMA16 __builtin_amdgcn_mfma_f32_16x16x32_bf16

// ---------------- prep: fp32 weights -> bf16 swizzled LDS chunk images ----------------
// w1img per (n,c): 32KB Bt1 [64 nn][256 kk]: val = U1[n][kk][c*64+nn], byte ^= (nn&7)<<4
// w2img per (n,c): 32KB Bt2 [256 nn][64 kk]: val = U2[n][c*64+kk][nn], byte ^= (nn&7)<<4
__global__ void prep_weights(const float* __restrict__ U1, const float* __restrict__ U2,
                             unsigned short* __restrict__ w1img, unsigned short* __restrict__ w2img)
{
    const int b = blockIdx.x;          // 0..127 : n*16 + c
    const int n = b >> 4, cch = b & 15;
    const int tid = threadIdx.x;       // 0..255
    char* img1 = (char*)(w1img) + ((size_t)b << 15);
    char* img2 = (char*)(w2img) + ((size_t)b << 15);
    const float* U1n = U1 + (size_t)n * DV * FF;
    const float* U2n = U2 + (size_t)n * FF * DV;
    #pragma unroll 4
    for (int e = 0; e < 64; ++e) {
        int kk = e * 4 + (tid >> 6);
        int nn = tid & 63;
        float v = U1n[(size_t)kk * FF + cch * 64 + nn];
        unsigned off = ((unsigned)(nn * 256 + kk) * 2u) ^ (unsigned)((nn & 7) << 4);
        *(unsigned short*)(img1 + off) = f2bf(v);
    }
    #pragma unroll 4
    for (int e = 0; e < 64; ++e) {
        int nn = tid;  // 0..255
        float v = U2n[(size_t)(cch * 64 + e) * DV + nn];
        unsigned off = ((unsigned)(nn * 64 + e) * 2u) ^ (unsigned)((nn & 7) << 4);
        *(unsigned short*)(img2 + off) = f2bf(v);
    }
}

// ---------------- main: producer/consumer wave-specialized fused kernel ----------------
// 16 waves: P = waves 0..7 (GEMM1 -> Hs), C = waves 8..15 (GEMM2, persistent acc2).
__global__ __launch_bounds__(1024, 4)
void belayer_main(const float* __restrict__ x,
                  const unsigned short* __restrict__ w1img,
                  const unsigned short* __restrict__ w2img,
                  const float* __restrict__ b1g, const float* __restrict__ b2g,
                  const float* __restrict__ lnw, const float* __restrict__ lnb,
                  float* __restrict__ out)
{
    __shared__ __align__(16) char LDS[LDS_BYTES];
    const int tid  = threadIdx.x;
    const int lane = tid & 63;
    const int wave = tid >> 6;            // 0..15
    const bool isP = (wave < 8);
    const int q = lane >> 4, c = lane & 15;
    const int n    = blockIdx.x & 7;      // branch == XCD affinity
    const int tile = blockIdx.x >> 3;
    const int row0 = tile * ROWS;
    const unsigned swz = (unsigned)((c & 7) << 4);

    // ---- staging setup: P stages B1 images, C stages B2 images (4 GLL x 16B each) ----
    const int sw = isP ? wave : (wave - 8);           // 0..7 within group
    const char* gbase = (isP ? (const char*)w1img : (const char*)w2img)
                        + ((size_t)(n * NCHUNK) << 15) + (sw << 12) + lane * 16;
    char* lbase = LDS + (isP ? L_B1 : L_B2) + (sw << 12);

#define STAGE(CH, HALF) do {                                        \
        const char* g_ = gbase + ((size_t)(CH) << 15);              \
        char* l_ = lbase + ((unsigned)(HALF) << 15);                \
        GLL(g_,        l_);        GLL(g_ + 1024, l_ + 1024);       \
        GLL(g_ + 2048, l_ + 2048); GLL(g_ + 3072, l_ + 3072);       \
    } while (0)

    // ---- P: GEMM1 geometry (4 rowgroups x 2 colgroups; tile 32 rows x 32 ffn) ----
    const int rowg = wave >> 1, colsel = wave & 1;
    // ---- C: GEMM2 geometry (2 rowgroups x 4 colgroups; tile 64 rows x 64 cols) ----
    const int rowg2 = (wave - 8) >> 2, colg2 = (wave - 8) & 3;

    bf16x8 A[2][8];   // P only: x rows resident (64 VGPR)
    if (isP) {
        STAGE(0, 0);  // prologue: B1[0] -> buf0
        #pragma unroll
        for (int rf = 0; rf < 2; ++rf) {
            const float* src = x + (((size_t)(row0 + rowg * 32 + rf * 16 + c)) * NBR + n) * DV + q * 8;
            #pragma unroll
            for (int ks = 0; ks < 8; ++ks) {
                f32x4 v0 = *(const f32x4*)(src + ks * 32);
                f32x4 v1 = *(const f32x4*)(src + ks * 32 + 4);
                bf16x8 h;
                h[0] = (short)f2bf(v0[0]); h[1] = (short)f2bf(v0[1]);
                h[2] = (short)f2bf(v0[2]); h[3] = (short)f2bf(v0[3]);
                h[4] = (short)f2bf(v1[0]); h[5] = (short)f2bf(v1[1]);
                h[6] = (short)f2bf(v1[2]); h[7] = (short)f2bf(v1[3]);
                A[rf][ks] = h;
            }
        }
    }

    // ---- precomputed swizzled LDS addresses ----
    // pattern: addr = ((linear_base + q*16) ^ swz) ^ ((ks&1)<<6) + hi-bit adds (safe: adds touch bits>=7 only)
    unsigned aB1[2], aW[4][2];
    #pragma unroll
    for (int cf = 0; cf < 2; ++cf) {
        unsigned nn = (unsigned)(colsel * 32 + cf * 16 + c);
        aB1[cf] = (nn * 512 + q * 16) ^ swz;
    }
    #pragma unroll
    for (int r = 0; r < 4; ++r)
        #pragma unroll
        for (int cf = 0; cf < 2; ++cf)
            aW[r][cf] = (unsigned)(((rowg * 32 + q * 4 + r) * 128 + (colsel * 32 + cf * 16 + c) * 2)
                                   ^ (((q * 4 + r) & 7) << 4));
    const unsigned aH  = (((unsigned)(rowg2 * 64 + c)) * 128 + q * 16) ^ swz;
    const unsigned aB2 = (((unsigned)(colg2 * 64 + c)) * 128 + q * 16) ^ swz;

    f32x4 acc2[4][4];  // C only: persistent GEMM2 accumulator (64 regs)
    #pragma unroll
    for (int i = 0; i < 4; ++i)
        #pragma unroll
        for (int j = 0; j < 4; ++j) acc2[i][j] = (f32x4){0.f, 0.f, 0.f, 0.f};

    __syncthreads();   // B1[0] staged & visible

    // ================= main loop: 17 phases, ONE barrier per phase =================
    // phase t: P computes G1[t] (t<=15), stages B1[t+1]; C computes G2[t-1] (t>=1), stages B2[t].
    for (int t = 0; t <= NCHUNK; ++t) {
        if (isP) {
            if (t < NCHUNK) {
                if (t + 1 < NCHUNK) STAGE(t + 1, (t + 1) & 1);
                float b1v0 = b1g[n * FF + t * 64 + colsel * 32 + c];
                float b1v1 = b1g[n * FF + t * 64 + colsel * 32 + 16 + c];
                const unsigned bOff = L_B1 + ((unsigned)(t & 1) << 15);
                f32x4 acc1[2][2];
                #pragma unroll
                for (int i = 0; i < 2; ++i)
                    #pragma unroll
                    for (int j = 0; j < 2; ++j) acc1[i][j] = (f32x4){0.f, 0.f, 0.f, 0.f};
                #pragma unroll
                for (int ks = 0; ks < 8; ++ks) {
                    const unsigned ka = (unsigned)((ks & 1) << 6);
                    const unsigned ko = bOff + (unsigned)(ks >> 1) * 128;
                    bf16x8 b0  = *(const bf16x8*)(LDS + ((aB1[0] ^ ka) + ko));
                    bf16x8 b1f = *(const bf16x8*)(LDS + ((aB1[1] ^ ka) + ko));
                    acc1[0][0] = MFMA16(A[0][ks], b0,  acc1[0][0], 0, 0, 0);
                    acc1[0][1] = MFMA16(A[0][ks], b1f, acc1[0][1], 0, 0, 0);
                    acc1[1][0] = MFMA16(A[1][ks], b0,  acc1[1][0], 0, 0, 0);
                    acc1[1][1] = MFMA16(A[1][ks], b1f, acc1[1][1], 0, 0, 0);
                }
                const unsigned hw = L_HS + ((unsigned)(t & 1) << 14);
                #pragma unroll
                for (int cf = 0; cf < 2; ++cf) {
                    float bv = cf ? b1v1 : b1v0;
                    #pragma unroll
                    for (int rf = 0; rf < 2; ++rf)
                        #pragma unroll
                        for (int r = 0; r < 4; ++r) {
                            float g = gelu_fast(acc1[rf][cf][r] + bv);
                            *(unsigned short*)(LDS + hw + aW[r][cf] + rf * 2048) = f2bf(g);
                        }
                }
            }
        } else {
            if (t < NCHUNK) STAGE(t, t & 1);
            if (t >= 1) {
                const unsigned hOff  = L_HS + ((unsigned)((t - 1) & 1) << 14);
                const unsigned b2Off = L_B2 + ((unsigned)((t - 1) & 1) << 15);
                #pragma unroll
                for (int ks = 0; ks < 2; ++ks) {
                    const unsigned ka = (unsigned)(ks << 6);
                    bf16x8 af[4], bf[4];
                    #pragma unroll
                    for (int rf = 0; rf < 4; ++rf)
                        af[rf] = *(const bf16x8*)(LDS + hOff + ((aH ^ ka) + rf * 2048));
                    #pragma unroll
                    for (int cf = 0; cf < 4; ++cf)
                        bf[cf] = *(const bf16x8*)(LDS + b2Off + ((aB2 ^ ka) + cf * 2048));
                    #pragma unroll
                    for (int rf = 0; rf < 4; ++rf)
                        #pragma unroll
                        for (int cf = 0; cf < 4; ++cf)
                            acc2[rf][cf] = MFMA16(af[rf], bf[cf], acc2[rf][cf], 0, 0, 0);
                }
            }
        }
        __syncthreads();   // drains this phase's GLLs (hidden under compute) + publishes LDS
    }

    // ================= epilogue (C waves; P just passes the barriers) =================
    float* Lred = (float*)(LDS + L_HS);   // 4KB scratch in Hs buf0 (last G2 read was buf1)
    float sA[4][4], sQ[4][4];
    if (!isP) {
        float b2v[4];
        #pragma unroll
        for (int cf = 0; cf < 4; ++cf) b2v[cf] = b2g[n * DV + colg2 * 64 + cf * 16 + c];
        #pragma unroll
        for (int rf = 0; rf < 4; ++rf)
            #pragma unroll
            for (int r = 0; r < 4; ++r) { sA[rf][r] = 0.f; sQ[rf][r] = 0.f; }
        #pragma unroll
        for (int rf = 0; rf < 4; ++rf)
            #pragma unroll
            for (int cf = 0; cf < 4; ++cf)
                #pragma unroll
                for (int r = 0; r < 4; ++r) {
                    float v = acc2[rf][cf][r] + b2v[cf];
                    acc2[rf][cf][r] = v;
                    sA[rf][r] += v;
                    sQ[rf][r] += v * v;
                }
        #pragma unroll
        for (int m = 1; m < 16; m <<= 1)
            #pragma unroll
            for (int rf = 0; rf < 4; ++rf)
                #pragma unroll
                for (int r = 0; r < 4; ++r) {
                    sA[rf][r] += __shfl_xor(sA[rf][r], m, 64);
                    sQ[rf][r] += __shfl_xor(sQ[rf][r], m, 64);
                }
        if (c == 0) {
            #pragma unroll
            for (int rf = 0; rf < 4; ++rf)
                #pragma unroll
                for (int r = 0; r < 4; ++r) {
                    int row = rowg2 * 64 + rf * 16 + q * 4 + r;
                    Lred[colg2 * 128 + row]       = sA[rf][r];
                    Lred[512 + colg2 * 128 + row] = sQ[rf][r];
                }
        }
    }
    __syncthreads();
    if (!isP) {
        float mu[4][4], rs[4][4];
        #pragma unroll
        for (int rf = 0; rf < 4; ++rf)
            #pragma unroll
            for (int r = 0; r < 4; ++r) {
                int row = rowg2 * 64 + rf * 16 + q * 4 + r;
                float ssum = Lred[row] + Lred[128 + row] + Lred[256 + row] + Lred[384 + row];
                float qsum = Lred[512 + row] + Lred[640 + row] + Lred[768 + row] + Lred[896 + row];
                float m_ = ssum * (1.0f / 256.0f);
                float var = qsum * (1.0f / 256.0f) - m_ * m_;
                mu[rf][r] = m_;
                rs[rf][r] = rsqrtf(var + 1e-5f);
            }
        #pragma unroll
        for (int cf = 0; cf < 4; ++cf) {
            int col = colg2 * 64 + cf * 16 + c;
            float lw = lnw[col];
            float lb = lnb[col];
            #pragma unroll
            for (int rf = 0; rf < 4; ++rf)
                #pragma unroll
                for (int r = 0; r < 4; ++r) {
                    int row = rowg2 * 64 + rf * 16 + q * 4 + r;
                    float v = (acc2[rf][cf][r] - mu[rf][r]) * rs[rf][r] * lw + lb;
                    float g = gelu_fast(v);
                    size_t oi = ((size_t)(row0 + row) * NBR + n) * DV + col;
                    out[oi] = x[oi] + g;
                }
        }
    }
#undef STAGE
}

extern "C" void kernel_launch(void* const* d_in, const int* in_sizes, int n_in,
                              void* d_out, int out_size, void* d_ws, size_t ws_size,
                              hipStream_t stream) {
    const float* x   = (const float*)d_in[0];
    const float* U1  = (const float*)d_in[1];
    const float* b1  = (const float*)d_in[2];
    const float* U2  = (const float*)d_in[3];
    const float* b2  = (const float*)d_in[4];
    const float* lnw = (const float*)d_in[5];
    const float* lnb = (const float*)d_in[6];
    float* out = (float*)d_out;

    unsigned short* w1img = (unsigned short*)d_ws;               // 4 MB
    unsigned short* w2img = w1img + (size_t)4 * 1024 * 1024 / 2; // 4 MB

    prep_weights<<<dim3(128), dim3(256), 0, stream>>>(U1, U2, w1img, w2img);
    belayer_main<<<dim3(1024), dim3(1024), 0, stream>>>(x, w1img, w2img, b1, b2, lnw, lnb, out);
}

// Round 6
// 278.959 us; speedup vs baseline: 2.3934x; 2.3934x over previous
//
#include <hip/hip_runtime.h>
#include <hip/hip_bf16.h>

#define NBR   8
#define DV    256    // VOCAB
#define FF    1024   // FFN
#define ROWS  128    // rows per block
#define NCHUNK 16    // FFN chunks of 64

// LDS (bytes): B1 dbuf 2x32K @0 | B2 dbuf 2x32K @64K | Hs 16K @128K | bias 4K @144K
#define L_B1   0
#define L_B2   65536
#define L_HS   131072
#define L_BIAS 147456
#define LDS_BYTES 151552

using bf16x8 = __attribute__((ext_vector_type(8))) short;
using f32x4  = __attribute__((ext_vector_type(4))) float;

__device__ __forceinline__ unsigned short f2bf(float f) {
    unsigned int u = __builtin_bit_cast(unsigned int, f);
    unsigned int r = (u + 0x7fffu + ((u >> 16) & 1u)) >> 16;
    return (unsigned short)r;
}
// gelu(x) ~= x * sigmoid(1.595769122x + 0.0713548163x^3), exp2 domain
__device__ __forceinline__ float gelu_fast(float x) {
    float x2 = x * x;
    float z  = x * fmaf(x2, -0.1029434959f, -2.3022078770f);
    float e  = __builtin_amdgcn_exp2f(z);
    return x * __builtin_amdgcn_rcpf(1.0f + e);
}

#define GLL(gsrc, ldst) __builtin_amdgcn_global_load_lds((const unsigned int*)(gsrc), (unsigned int*)(ldst), 16, 0, 0)
#define MFMA16 __builtin_amdgcn_mfma_f32_16x16x32_bf16

#define CLOBBER() asm volatile("" ::: "memory")
#define BAR()     do { CLOBBER(); __builtin_amdgcn_s_barrier(); CLOBBER(); } while (0)
#define LGKM0()   do { asm volatile("s_waitcnt lgkmcnt(0)" ::: "memory"); __builtin_amdgcn_sched_barrier(0); } while (0)
#define VMCNT(N)  asm volatile("s_waitcnt vmcnt(" #N ")" ::: "memory")

// ---------------- prep: fp32 weights -> bf16 swizzled LDS chunk images ----------------
// w1img per (n,c): 32KB Bt1 [64 nn][256 kk]: val = U1[n][kk][c*64+nn], byte ^= (nn&7)<<4
// w2img per (n,c): 32KB Bt2 [256 nn][64 kk]: val = U2[n][c*64+kk][nn], byte ^= (nn&7)<<4
__global__ void prep_weights(const float* __restrict__ U1, const float* __restrict__ U2,
                             unsigned short* __restrict__ w1img, unsigned short* __restrict__ w2img)
{
    const int b = blockIdx.x;          // 0..127 : n*16 + c
    const int n = b >> 4, cch = b & 15;
    const int tid = threadIdx.x;       // 0..255
    char* img1 = (char*)(w1img) + ((size_t)b << 15);
    char* img2 = (char*)(w2img) + ((size_t)b << 15);
    const float* U1n = U1 + (size_t)n * DV * FF;
    const float* U2n = U2 + (size_t)n * FF * DV;
    #pragma unroll 4
    for (int e = 0; e < 64; ++e) {
        int kk = e * 4 + (tid >> 6);
        int nn = tid & 63;
        float v = U1n[(size_t)kk * FF + cch * 64 + nn];
        unsigned off = ((unsigned)(nn * 256 + kk) * 2u) ^ (unsigned)((nn & 7) << 4);
        *(unsigned short*)(img1 + off) = f2bf(v);
    }
    #pragma unroll 4
    for (int e = 0; e < 64; ++e) {
        int nn = tid;  // 0..255
        float v = U2n[(size_t)(cch * 64 + e) * DV + nn];
        unsigned off = ((unsigned)(nn * 64 + e) * 2u) ^ (unsigned)((nn & 7) << 4);
        *(unsigned short*)(img2 + off) = f2bf(v);
    }
}

// ---------------- main: 6-phase fine-grained schedule (m201-style) ----------------
__global__ __launch_bounds__(512, 2)
void belayer_main(const float* __restrict__ x,
                  const unsigned short* __restrict__ w1img,
                  const unsigned short* __restrict__ w2img,
                  const float* __restrict__ b1g, const float* __restrict__ b2g,
                  const float* __restrict__ lnw, const float* __restrict__ lnb,
                  float* __restrict__ out)
{
    __shared__ __align__(16) char LDS[LDS_BYTES];
    const int tid  = threadIdx.x;
    const int lane = tid & 63;
    const int wave = tid >> 6;          // 0..7
    const int q = lane >> 4, c = lane & 15;
    const int n    = blockIdx.x & 7;    // branch == XCD affinity
    const int tile = blockIdx.x >> 3;
    const int row0 = tile * ROWS;
    const int rowgrp = wave >> 1, colsel = wave & 1;   // GEMM1: 32 rows x 32 ffn per wave
    const int rowg2  = wave >> 2, colg2  = wave & 3;   // GEMM2: 64 rows x 64 cols per wave
    const unsigned swz = (unsigned)((c & 7) << 4);

    const char* g1base = (const char*)w1img + ((size_t)(n * NCHUNK) << 15) + (wave << 12) + lane * 16;
    const char* g2base = (const char*)w2img + ((size_t)(n * NCHUNK) << 15) + (wave << 12) + lane * 16;

    // ---- prologue: stage B1[0], B2[0] (order: B1 group first, then B2) ----
    #pragma unroll
    for (int i = 0; i < 4; ++i) GLL(g1base + (i << 10), LDS + L_B1 + (wave << 12) + (i << 10));
    #pragma unroll
    for (int i = 0; i < 4; ++i) GLL(g2base + (i << 10), LDS + L_B2 + (wave << 12) + (i << 10));

    // ---- GEMM1 A-frags straight from global x (resident: 64 VGPR) ----
    bf16x8 A[2][8];
    #pragma unroll
    for (int rf = 0; rf < 2; ++rf) {
        const float* src = x + (((size_t)(row0 + rowgrp * 32 + rf * 16 + c)) * NBR + n) * DV + q * 8;
        #pragma unroll
        for (int ks = 0; ks < 8; ++ks) {
            f32x4 v0 = *(const f32x4*)(src + ks * 32);
            f32x4 v1 = *(const f32x4*)(src + ks * 32 + 4);
            bf16x8 h;
            h[0] = (short)f2bf(v0[0]); h[1] = (short)f2bf(v0[1]);
            h[2] = (short)f2bf(v0[2]); h[3] = (short)f2bf(v0[3]);
            h[4] = (short)f2bf(v1[0]); h[5] = (short)f2bf(v1[1]);
            h[6] = (short)f2bf(v1[2]); h[7] = (short)f2bf(v1[3]);
            A[rf][ks] = h;
        }
    }
    // ---- bias b1[n] -> LDS (so no global loads perturb vmcnt counts in the loop) ----
    {
        float* bl = (float*)(LDS + L_BIAS);
        bl[tid]       = b1g[n * FF + tid];
        bl[tid + 512] = b1g[n * FF + tid + 512];
    }
    __syncthreads();   // full drain: B1[0]/B2[0]/bias published; vmcnt==0 here

    // ---- precomputed swizzled LDS addresses ----
    const unsigned nn01 = (unsigned)(colsel * 32 + c);
    const unsigned aB1e = (nn01 * 512 + q * 16) ^ swz;
    const unsigned aB1o = (nn01 * 512 + q * 16 + 64) ^ swz;
    const unsigned rr0  = (unsigned)(rowg2 * 64 + c);
    const unsigned aHe  = (rr0 * 128 + q * 16) ^ swz;
    const unsigned aHo  = (rr0 * 128 + q * 16 + 64) ^ swz;
    const unsigned nn02 = (unsigned)(colg2 * 64 + c);
    const unsigned aB2e = (nn02 * 128 + q * 16) ^ swz;
    const unsigned aB2o = (nn02 * 128 + q * 16 + 64) ^ swz;
    unsigned aW[4][2];
    #pragma unroll
    for (int r = 0; r < 4; ++r)
        #pragma unroll
        for (int cf = 0; cf < 2; ++cf)
            aW[r][cf] = (unsigned)(((rowgrp * 32 + q * 4 + r) * 128 + (colsel * 32 + cf * 16 + c) * 2)
                                   ^ (((q * 4 + r) & 7) << 4));

    f32x4 acc2[4][4];
    #pragma unroll
    for (int i = 0; i < 4; ++i)
        #pragma unroll
        for (int j = 0; j < 4; ++j) acc2[i][j] = (f32x4){0.f, 0.f, 0.f, 0.f};

    #pragma unroll 2
    for (int t = 0; t < NCHUNK; ++t) {
        const int tsrc = (t < NCHUNK - 1) ? (t + 1) : (NCHUNK - 1);  // clamp: dummy reload
        const unsigned b1Off = L_B1 + ((unsigned)(t & 1) << 15);
        const unsigned b2Off = L_B2 + ((unsigned)(t & 1) << 15);

        // ========== PH1: publish B1[t]; read G1 ks0-3; issue ALL t+1 staging ==========
        VMCNT(4);                 // outstanding: B1[t](4,old)+B2[t](4) -> drain B1[t] exactly
        BAR();                    // B1[t] visible
        bf16x8 p0[4], p1[4];
        #pragma unroll
        for (int ks = 0; ks < 4; ++ks) {
            const unsigned bbA = ((ks & 1) ? aB1o : aB1e) + b1Off + (unsigned)(ks >> 1) * 128;
            p0[ks] = *(const bf16x8*)(LDS + bbA);
            p1[ks] = *(const bf16x8*)(LDS + bbA + 8192);
        }
        {   // B1[t+1] first, then B2[t+1] — order defines the vmcnt(4)/(8) drain split
            const char* g1 = g1base + ((size_t)tsrc << 15);
            char* l1 = LDS + L_B1 + (((t + 1) & 1) << 15) + (wave << 12);
            #pragma unroll
            for (int i = 0; i < 4; ++i) GLL(g1 + (i << 10), l1 + (i << 10));
            const char* g2 = g2base + ((size_t)tsrc << 15);
            char* l2 = LDS + L_B2 + (((t + 1) & 1) << 15) + (wave << 12);
            #pragma unroll
            for (int i = 0; i < 4; ++i) GLL(g2 + (i << 10), l2 + (i << 10));
        }
        BAR();

        // ========== PH2: MFMA G1 ks0-3 ; read G1 ks4-7 + bias ==========
        f32x4 acc1[2][2];
        #pragma unroll
        for (int i = 0; i < 2; ++i)
            #pragma unroll
            for (int j = 0; j < 2; ++j) acc1[i][j] = (f32x4){0.f, 0.f, 0.f, 0.f};
        LGKM0();
        __builtin_amdgcn_s_setprio(1);
        #pragma unroll
        for (int ks = 0; ks < 4; ++ks) {
            acc1[0][0] = MFMA16(A[0][ks], p0[ks], acc1[0][0], 0, 0, 0);
            acc1[0][1] = MFMA16(A[0][ks], p1[ks], acc1[0][1], 0, 0, 0);
            acc1[1][0] = MFMA16(A[1][ks], p0[ks], acc1[1][0], 0, 0, 0);
            acc1[1][1] = MFMA16(A[1][ks], p1[ks], acc1[1][1], 0, 0, 0);
        }
        __builtin_amdgcn_s_setprio(0);
        bf16x8 r0[4], r1[4];
        #pragma unroll
        for (int ks = 4; ks < 8; ++ks) {
            const unsigned bbA = ((ks & 1) ? aB1o : aB1e) + b1Off + (unsigned)(ks >> 1) * 128;
            r0[ks - 4] = *(const bf16x8*)(LDS + bbA);
            r1[ks - 4] = *(const bf16x8*)(LDS + bbA + 8192);
        }
        float b1v0 = *(const float*)(LDS + L_BIAS + (unsigned)(t * 64 + colsel * 32 + c) * 4);
        float b1v1 = *(const float*)(LDS + L_BIAS + (unsigned)(t * 64 + colsel * 32 + 16 + c) * 4);
        BAR();

        // ========== PH3: MFMA G1 ks4-7 ; gelu -> Hs ; publish Hs + B2[t] ==========
        LGKM0();
        __builtin_amdgcn_s_setprio(1);
        #pragma unroll
        for (int ks = 0; ks < 4; ++ks) {
            acc1[0][0] = MFMA16(A[0][ks + 4], r0[ks], acc1[0][0], 0, 0, 0);
            acc1[0][1] = MFMA16(A[0][ks + 4], r1[ks], acc1[0][1], 0, 0, 0);
            acc1[1][0] = MFMA16(A[1][ks + 4], r0[ks], acc1[1][0], 0, 0, 0);
            acc1[1][1] = MFMA16(A[1][ks + 4], r1[ks], acc1[1][1], 0, 0, 0);
        }
        __builtin_amdgcn_s_setprio(0);
        #pragma unroll
        for (int cf = 0; cf < 2; ++cf) {
            float bv = cf ? b1v1 : b1v0;
            #pragma unroll
            for (int rf = 0; rf < 2; ++rf)
                #pragma unroll
                for (int r = 0; r < 4; ++r) {
                    float g = gelu_fast(acc1[rf][cf][r] + bv);
                    *(unsigned short*)(LDS + L_HS + aW[r][cf] + rf * 2048) = f2bf(g);
                }
        }
        LGKM0();                  // drain Hs writes before publish
        VMCNT(8);                 // outstanding: B2[t](4,old)+B1[t+1](4)+B2[t+1](4) -> drain B2[t]
        BAR();                    // Hs + B2[t] visible

        // ========== PH4: read G2 ks0 ==========
        bf16x8 af0[4], bf0[4];
        #pragma unroll
        for (int rf = 0; rf < 4; ++rf) af0[rf] = *(const bf16x8*)(LDS + L_HS + aHe + rf * 2048);
        #pragma unroll
        for (int cf = 0; cf < 4; ++cf) bf0[cf] = *(const bf16x8*)(LDS + b2Off + aB2e + cf * 2048);
        BAR();

        // ========== PH5: MFMA G2 ks0 ; read G2 ks1 ==========
        LGKM0();
        __builtin_amdgcn_s_setprio(1);
        #pragma unroll
        for (int rf = 0; rf < 4; ++rf)
            #pragma unroll
            for (int cf = 0; cf < 4; ++cf)
                acc2[rf][cf] = MFMA16(af0[rf], bf0[cf], acc2[rf][cf], 0, 0, 0);
        __builtin_amdgcn_s_setprio(0);
        bf16x8 af1[4], bf1[4];
        #pragma unroll
        for (int rf = 0; rf < 4; ++rf) af1[rf] = *(const bf16x8*)(LDS + L_HS + aHo + rf * 2048);
        #pragma unroll
        for (int cf = 0; cf < 4; ++cf) bf1[cf] = *(const bf16x8*)(LDS + b2Off + aB2o + cf * 2048);
        BAR();

        // ========== PH6: MFMA G2 ks1 (no trailing barrier; next PH1 syncs) ==========
        LGKM0();
        __builtin_amdgcn_s_setprio(1);
        #pragma unroll
        for (int rf = 0; rf < 4; ++rf)
            #pragma unroll
            for (int cf = 0; cf < 4; ++cf)
                acc2[rf][cf] = MFMA16(af1[rf], bf1[cf], acc2[rf][cf], 0, 0, 0);
        __builtin_amdgcn_s_setprio(0);
    }

    __syncthreads();   // full drain (incl. dummy tail GLLs); LDS free for Lred

    // ---- epilogue: skip loads, +b2, cross-wave LN(256), gelu, +skip, store ----
    float skp[4][4][4];
    #pragma unroll
    for (int rf = 0; rf < 4; ++rf)
        #pragma unroll
        for (int r = 0; r < 4; ++r) {
            const float* xr = x + ((size_t)(row0 + rowg2 * 64 + rf * 16 + q * 4 + r) * NBR + n) * DV;
            #pragma unroll
            for (int cf = 0; cf < 4; ++cf)
                skp[rf][cf][r] = xr[colg2 * 64 + cf * 16 + c];
        }
    float b2v[4];
    #pragma unroll
    for (int cf = 0; cf < 4; ++cf) b2v[cf] = b2g[n * DV + colg2 * 64 + cf * 16 + c];

    float sA[4][4], sQ[4][4];
    #pragma unroll
    for (int rf = 0; rf < 4; ++rf)
        #pragma unroll
        for (int r = 0; r < 4; ++r) { sA[rf][r] = 0.f; sQ[rf][r] = 0.f; }
    #pragma unroll
    for (int rf = 0; rf < 4; ++rf)
        #pragma unroll
        for (int cf = 0; cf < 4; ++cf)
            #pragma unroll
            for (int r = 0; r < 4; ++r) {
                float v = acc2[rf][cf][r] + b2v[cf];
                acc2[rf][cf][r] = v;
                sA[rf][r] += v;
                sQ[rf][r] += v * v;
            }
    #pragma unroll
    for (int m = 1; m < 16; m <<= 1)
        #pragma unroll
        for (int rf = 0; rf < 4; ++rf)
            #pragma unroll
            for (int r = 0; r < 4; ++r) {
                sA[rf][r] += __shfl_xor(sA[rf][r], m, 64);
                sQ[rf][r] += __shfl_xor(sQ[rf][r], m, 64);
            }
    float* Lred = (float*)(LDS + L_HS);
    if (c == 0) {
        #pragma unroll
        for (int rf = 0; rf < 4; ++rf)
            #pragma unroll
            for (int r = 0; r < 4; ++r) {
                int row = rowg2 * 64 + rf * 16 + q * 4 + r;
                Lred[colg2 * 128 + row]       = sA[rf][r];
                Lred[512 + colg2 * 128 + row] = sQ[rf][r];
            }
    }
    __syncthreads();
    float mu[4][4], rs[4][4];
    #pragma unroll
    for (int rf = 0; rf < 4; ++rf)
        #pragma unroll
        for (int r = 0; r < 4; ++r) {
            int row = rowg2 * 64 + rf * 16 + q * 4 + r;
            float ssum = Lred[row] + Lred[128 + row] + Lred[256 + row] + Lred[384 + row];
            float qsum = Lred[512 + row] + Lred[640 + row] + Lred[768 + row] + Lred[896 + row];
            float m_ = ssum * (1.0f / 256.0f);
            float var = qsum * (1.0f / 256.0f) - m_ * m_;
            mu[rf][r] = m_;
            rs[rf][r] = rsqrtf(var + 1e-5f);
        }
    #pragma unroll
    for (int cf = 0; cf < 4; ++cf) {
        int col = colg2 * 64 + cf * 16 + c;
        float lw = lnw[col];
        float lb = lnb[col];
        #pragma unroll
        for (int rf = 0; rf < 4; ++rf)
            #pragma unroll
            for (int r = 0; r < 4; ++r) {
                int row = rowg2 * 64 + rf * 16 + q * 4 + r;
                float v = (acc2[rf][cf][r] - mu[rf][r]) * rs[rf][r] * lw + lb;
                float g = gelu_fast(v);
                out[((size_t)(row0 + row) * NBR + n) * DV + col] = skp[rf][cf][r] + g;
            }
    }
}

extern "C" void kernel_launch(void* const* d_in, const int* in_sizes, int n_in,
                              void* d_out, int out_size, void* d_ws, size_t ws_size,
                              hipStream_t stream) {
    const float* x   = (const float*)d_in[0];
    const float* U1  = (const float*)d_in[1];
    const float* b1  = (const float*)d_in[2];
    const float* U2  = (const float*)d_in[3];
    const float* b2  = (const float*)d_in[4];
    const float* lnw = (const float*)d_in[5];
    const float* lnb = (const float*)d_in[6];
    float* out = (float*)d_out;

    unsigned short* w1img = (unsigned short*)d_ws;               // 4 MB
    unsigned short* w2img = w1img + (size_t)4 * 1024 * 1024 / 2; // 4 MB

    prep_weights<<<dim3(128), dim3(256), 0, stream>>>(U1, U2, w1img, w2img);
    belayer_main<<<dim3(1024), dim3(512), 0, stream>>>(x, w1img, w2img, b1, b2, lnw, lnb, out);
}